// Round 1
// baseline (1225.579 us; speedup 1.0000x reference)
//
#include <hip/hip_runtime.h>
#include <hip/hip_bf16.h>
#include <math.h>

// ---------- types ----------
typedef __attribute__((ext_vector_type(4))) float  f32x4;
typedef __attribute__((ext_vector_type(8))) __bf16 bf16x8;
typedef __attribute__((ext_vector_type(4))) __bf16 bf16x4;

#define HIDDEN 1024
#define HEADS 16
#define HDIM 64
#define BATCH 2
#define SEQ 2048
#define ROWS (BATCH*SEQ)          // 4096
#define BH (BATCH*HEADS)          // 32
#define OUT0_ELEMS ((size_t)ROWS*HIDDEN)                    // 4,194,304
#define PW_ELEMS   ((size_t)BH*SEQ*SEQ)                     // 134,217,728

// ---------- async global->LDS (16B per lane) ----------
__device__ __forceinline__ void gload_lds16(const void* g, void* l) {
    __builtin_amdgcn_global_load_lds(
        (const __attribute__((address_space(1))) void*)g,
        (__attribute__((address_space(3))) void*)l,
        16, 0, 0);
}

// ---------- cast fp32 -> bf16 (vector x4) ----------
__global__ void cast_f32_bf16(const float* __restrict__ in, __bf16* __restrict__ out, int n4) {
    int i = blockIdx.x * blockDim.x + threadIdx.x;
    if (i >= n4) return;
    float4 v = ((const float4*)in)[i];
    bf16x4 o = { (__bf16)v.x, (__bf16)v.y, (__bf16)v.z, (__bf16)v.w };
    ((bf16x4*)out)[i] = o;
}

// ---------- RoPE tables ----------
__global__ void rope_tables(float* __restrict__ cosT, float* __restrict__ sinT) {
    int i = blockIdx.x * blockDim.x + threadIdx.x;   // 65536 = 2048*32
    if (i >= SEQ * 32) return;
    int s = i >> 5, f = i & 31;
    float inv = (float)pow(10000.0, -(double)f / 32.0);
    float ang = (float)s * inv;
    cosT[i] = cosf(ang);
    sinT[i] = sinf(ang);
}

// ---------- MFMA GEMM: C[m][n] = sum_k A[m][k]*Bt[n][k] + bias[n] ----------
// A: MxK bf16 row-major, Bt: NxK bf16 row-major, C fp32. 128x128 tile, BK=32.
__global__ __launch_bounds__(256) void gemm_bt(const __bf16* __restrict__ A,
                                               const __bf16* __restrict__ Bt,
                                               const float* __restrict__ bias,
                                               float* __restrict__ C,
                                               int M, int N, int K) {
    __shared__ __bf16 As[128 * 32];
    __shared__ __bf16 Bs[128 * 32];
    const int tid = threadIdx.x, lane = tid & 63, wid = tid >> 6;
    const int wr = wid >> 1, wc = wid & 1;
    const int fr = lane & 15, fq = lane >> 4;
    const int row0 = blockIdx.x * 128, col0 = blockIdx.y * 128;

    f32x4 acc[4][4] = {};
    for (int k0 = 0; k0 < K; k0 += 32) {
        #pragma unroll
        for (int c2 = 0; c2 < 2; ++c2) {
            int ob = wid * 2048 + c2 * 1024;       // wave-uniform LDS byte base
            int o  = ob + lane * 16;               // this lane's byte
            int r  = o >> 6, cb = o & 63;          // row (64B per row), byte-in-row
            gload_lds16(A  + (size_t)(row0 + r) * K + k0 + (cb >> 1), (char*)As + ob);
            gload_lds16(Bt + (size_t)(col0 + r) * K + k0 + (cb >> 1), (char*)Bs + ob);
        }
        __syncthreads();
        bf16x8 af[4], bfr[4];
        #pragma unroll
        for (int m = 0; m < 4; ++m) af[m]  = *(const bf16x8*)(As + (wr * 64 + m * 16 + fr) * 32 + fq * 8);
        #pragma unroll
        for (int n = 0; n < 4; ++n) bfr[n] = *(const bf16x8*)(Bs + (wc * 64 + n * 16 + fr) * 32 + fq * 8);
        #pragma unroll
        for (int m = 0; m < 4; ++m)
            #pragma unroll
            for (int n = 0; n < 4; ++n)
                acc[m][n] = __builtin_amdgcn_mfma_f32_16x16x32_bf16(af[m], bfr[n], acc[m][n], 0, 0, 0);
        __syncthreads();
    }
    #pragma unroll
    for (int m = 0; m < 4; ++m)
        #pragma unroll
        for (int n = 0; n < 4; ++n) {
            int col = col0 + wc * 64 + n * 16 + fr;
            float bv = bias[col];
            #pragma unroll
            for (int j = 0; j < 4; ++j) {
                int row = row0 + wr * 64 + m * 16 + fq * 4 + j;
                C[(size_t)row * N + col] = acc[m][n][j] + bv;
            }
        }
}

// ---------- RoPE + relayout Q/K: proj fp32 [4096][1024] -> out bf16 [bh][s][64] ----------
__global__ void rope_relayout(const float* __restrict__ proj,
                              const float* __restrict__ cosT, const float* __restrict__ sinT,
                              __bf16* __restrict__ out) {
    int idx = blockIdx.x * blockDim.x + threadIdx.x;   // pair index, 4096*512
    if (idx >= ROWS * 512) return;
    int m = idx >> 9, p = idx & 511;
    int h = p >> 5, i = p & 31;
    int b = m >> 11, s = m & 2047;
    float x1 = proj[(size_t)m * HIDDEN + h * 64 + 2 * i];
    float x2 = proj[(size_t)m * HIDDEN + h * 64 + 2 * i + 1];
    float c = cosT[s * 32 + i], sn = sinT[s * 32 + i];
    size_t o = ((size_t)(b * HEADS + h) * SEQ + s) * 64 + 2 * i;
    out[o]     = (__bf16)(x1 * c - x2 * sn);
    out[o + 1] = (__bf16)(x1 * sn + x2 * c);
}

// ---------- V relayout (transposed): proj fp32 [4096][1024] -> Vt bf16 [bh][64][2048] ----------
__global__ void v_relayout(const float* __restrict__ proj, __bf16* __restrict__ Vt) {
    int idx = blockIdx.x * blockDim.x + threadIdx.x;   // 4096*1024
    if (idx >= ROWS * HIDDEN) return;
    int m = idx >> 10, c = idx & 1023;
    int h = c >> 6, d = c & 63;
    int b = m >> 11, s = m & 2047;
    Vt[((size_t)(b * HEADS + h) * 64 + d) * SEQ + s] = (__bf16)proj[idx];
}

// ---------- attention kernel A: raw masked scores + online (m,l) stats ----------
// grid (32 qtiles, 32 bh), 256 thr = 4 waves x 16 q-rows
__global__ __launch_bounds__(256) void attn_scores(const __bf16* __restrict__ Qb,
                                                   const __bf16* __restrict__ Kb,
                                                   float* __restrict__ P,
                                                   float* __restrict__ m_arr,
                                                   float* __restrict__ l_arr) {
    const int qt = blockIdx.x, bh = blockIdx.y;
    const int lane = threadIdx.x & 63, w = threadIdx.x >> 6;
    const int fr = lane & 15, fq = lane >> 4;
    const int rowBase = qt * 64 + w * 16;

    const size_t qoff = ((size_t)bh * SEQ + rowBase + fr) * 64;
    bf16x8 aq0 = *(const bf16x8*)(Qb + qoff + fq * 8);
    bf16x8 aq1 = *(const bf16x8*)(Qb + qoff + 32 + fq * 8);

    float mrow[4] = { -INFINITY, -INFINITY, -INFINITY, -INFINITY };
    float lrow[4] = { 0.f, 0.f, 0.f, 0.f };
    const int nkt16 = (rowBase / 32 + 1) * 2;   // column coverage matches kernel B

    for (int kt = 0; kt < nkt16; ++kt) {
        const size_t koff = ((size_t)bh * SEQ + kt * 16 + fr) * 64;
        bf16x8 bk0 = *(const bf16x8*)(Kb + koff + fq * 8);
        bf16x8 bk1 = *(const bf16x8*)(Kb + koff + 32 + fq * 8);
        f32x4 sc = { 0.f, 0.f, 0.f, 0.f };
        sc = __builtin_amdgcn_mfma_f32_16x16x32_bf16(aq0, bk0, sc, 0, 0, 0);
        sc = __builtin_amdgcn_mfma_f32_16x16x32_bf16(aq1, bk1, sc, 0, 0, 0);
        int col = kt * 16 + fr;
        #pragma unroll
        for (int j = 0; j < 4; ++j) {
            int row = rowBase + fq * 4 + j;
            float s = sc[j] * 0.125f;
            if (col > row) s = -1e9f;
            float nm = fmaxf(mrow[j], s);
            lrow[j] = lrow[j] * __expf(mrow[j] - nm) + __expf(s - nm);
            mrow[j] = nm;
            P[((size_t)bh * SEQ + row) * SEQ + col] = s;
        }
    }
    // reduce across the 16 lanes holding the row's columns (lane bits 0..3)
    #pragma unroll
    for (int j = 0; j < 4; ++j) {
        float m = mrow[j], l = lrow[j];
        #pragma unroll
        for (int d = 1; d < 16; d <<= 1) {
            float mo = __shfl_xor(m, d, 64);
            float lo = __shfl_xor(l, d, 64);
            float nm = fmaxf(m, mo);
            l = l * __expf(m - nm) + lo * __expf(mo - nm);
            m = nm;
        }
        if (fr == 0) {
            int row = rowBase + fq * 4 + j;
            m_arr[(size_t)bh * SEQ + row] = m;
            l_arr[(size_t)bh * SEQ + row] = l;
        }
    }
}

// ---------- attention kernel B: normalize P + PV MFMA -> attn_out bf16 ----------
__global__ __launch_bounds__(256) void attn_pv(float* __restrict__ P,
                                               const __bf16* __restrict__ Vt,
                                               const float* __restrict__ m_arr,
                                               const float* __restrict__ l_arr,
                                               __bf16* __restrict__ aout) {
    const int qt = blockIdx.x, bh = blockIdx.y;
    const int lane = threadIdx.x & 63, w = threadIdx.x >> 6;
    const int fr = lane & 15, fq = lane >> 4;
    const int rowBase = qt * 64 + w * 16;
    const int row = rowBase + fr;                     // A-fragment row
    const float m = m_arr[(size_t)bh * SEQ + row];
    const float linv = 1.0f / l_arr[(size_t)bh * SEQ + row];
    float* Pr = P + ((size_t)bh * SEQ + row) * SEQ;
    const int nkt32 = rowBase / 32 + 1;

    f32x4 acc[4] = {};
    for (int kt = 0; kt < nkt32; ++kt) {
        float4 s0 = *(const float4*)(Pr + kt * 32 + fq * 8);
        float4 s1 = *(const float4*)(Pr + kt * 32 + fq * 8 + 4);
        float p0 = __expf(s0.x - m) * linv;
        float p1 = __expf(s0.y - m) * linv;
        float p2 = __expf(s0.z - m) * linv;
        float p3 = __expf(s0.w - m) * linv;
        float p4 = __expf(s1.x - m) * linv;
        float p5 = __expf(s1.y - m) * linv;
        float p6 = __expf(s1.z - m) * linv;
        float p7 = __expf(s1.w - m) * linv;
        *(float4*)(Pr + kt * 32 + fq * 8)     = float4{ p0, p1, p2, p3 };
        *(float4*)(Pr + kt * 32 + fq * 8 + 4) = float4{ p4, p5, p6, p7 };
        bf16x8 pa = { (__bf16)p0, (__bf16)p1, (__bf16)p2, (__bf16)p3,
                      (__bf16)p4, (__bf16)p5, (__bf16)p6, (__bf16)p7 };
        #pragma unroll
        for (int nd = 0; nd < 4; ++nd) {
            bf16x8 bv = *(const bf16x8*)(Vt + ((size_t)bh * 64 + nd * 16 + fr) * SEQ + kt * 32 + fq * 8);
            acc[nd] = __builtin_amdgcn_mfma_f32_16x16x32_bf16(pa, bv, acc[nd], 0, 0, 0);
        }
    }
    const int b = bh >> 4, h = bh & 15;
    #pragma unroll
    for (int nd = 0; nd < 4; ++nd)
        #pragma unroll
        for (int j = 0; j < 4; ++j) {
            int qrow = rowBase + fq * 4 + j;
            int d = nd * 16 + fr;
            aout[((size_t)(b * SEQ + qrow)) * HIDDEN + h * 64 + d] = (__bf16)acc[nd][j];
        }
}

// ---------- host launch ----------
extern "C" void kernel_launch(void* const* d_in, const int* in_sizes, int n_in,
                              void* d_out, int out_size, void* d_ws, size_t ws_size,
                              hipStream_t stream) {
    const float* query = (const float*)d_in[0];
    const float* key   = (const float*)d_in[1];
    const float* value = (const float*)d_in[2];
    const float* Wq = (const float*)d_in[3];
    const float* bq = (const float*)d_in[4];
    const float* Wk = (const float*)d_in[5];
    const float* bk = (const float*)d_in[6];
    const float* Wv = (const float*)d_in[7];
    const float* bv = (const float*)d_in[8];
    const float* Wo = (const float*)d_in[9];
    const float* bo = (const float*)d_in[10];

    float* out0 = (float*)d_out;                       // [4096][1024]
    float* P    = (float*)d_out + OUT0_ELEMS;          // [32][2048][2048]

    // ---- carve workspace ----
    char* p = (char*)d_ws;
    auto alloc = [&](size_t bytes) { char* r = p; p += (bytes + 255) & ~(size_t)255; return r; };
    float*  cosT = (float*)alloc(SEQ * 32 * 4);
    float*  sinT = (float*)alloc(SEQ * 32 * 4);
    __bf16* Xq   = (__bf16*)alloc(OUT0_ELEMS * 2);
    __bf16* Xk   = (__bf16*)alloc(OUT0_ELEMS * 2);
    __bf16* Xv   = (__bf16*)alloc(OUT0_ELEMS * 2);
    __bf16* Wqb  = (__bf16*)alloc((size_t)HIDDEN * HIDDEN * 2);
    __bf16* Wkb  = (__bf16*)alloc((size_t)HIDDEN * HIDDEN * 2);
    __bf16* Wvb  = (__bf16*)alloc((size_t)HIDDEN * HIDDEN * 2);
    __bf16* Wob  = (__bf16*)alloc((size_t)HIDDEN * HIDDEN * 2);
    float*  proj = (float*)alloc(OUT0_ELEMS * 4);
    __bf16* Qb   = (__bf16*)alloc((size_t)BH * SEQ * 64 * 2);
    __bf16* Kb   = (__bf16*)alloc((size_t)BH * SEQ * 64 * 2);
    __bf16* Vt   = (__bf16*)alloc((size_t)BH * SEQ * 64 * 2);
    float*  m_arr = (float*)alloc((size_t)BH * SEQ * 4);
    float*  l_arr = (float*)alloc((size_t)BH * SEQ * 4);
    __bf16* aout = (__bf16*)alloc(OUT0_ELEMS * 2);

    // zero the attention-weights region (upper triangle stays 0)
    hipMemsetAsync(P, 0, PW_ELEMS * 4, stream);

    // tables
    rope_tables<<<(SEQ * 32 + 255) / 256, 256, 0, stream>>>(cosT, sinT);

    // casts
    cast_f32_bf16<<<(ROWS * HIDDEN / 4 + 255) / 256, 256, 0, stream>>>(query, Xq, ROWS * HIDDEN / 4);
    cast_f32_bf16<<<(ROWS * HIDDEN / 4 + 255) / 256, 256, 0, stream>>>(key,   Xk, ROWS * HIDDEN / 4);
    cast_f32_bf16<<<(ROWS * HIDDEN / 4 + 255) / 256, 256, 0, stream>>>(value, Xv, ROWS * HIDDEN / 4);
    cast_f32_bf16<<<(HIDDEN * HIDDEN / 4 + 255) / 256, 256, 0, stream>>>(Wq, Wqb, HIDDEN * HIDDEN / 4);
    cast_f32_bf16<<<(HIDDEN * HIDDEN / 4 + 255) / 256, 256, 0, stream>>>(Wk, Wkb, HIDDEN * HIDDEN / 4);
    cast_f32_bf16<<<(HIDDEN * HIDDEN / 4 + 255) / 256, 256, 0, stream>>>(Wv, Wvb, HIDDEN * HIDDEN / 4);
    cast_f32_bf16<<<(HIDDEN * HIDDEN / 4 + 255) / 256, 256, 0, stream>>>(Wo, Wob, HIDDEN * HIDDEN / 4);

    dim3 ggemm(ROWS / 128, HIDDEN / 128);

    // Q projection -> RoPE -> Qb
    gemm_bt<<<ggemm, 256, 0, stream>>>(Xq, Wqb, bq, proj, ROWS, HIDDEN, HIDDEN);
    rope_relayout<<<(ROWS * 512 + 255) / 256, 256, 0, stream>>>(proj, cosT, sinT, Qb);
    // K projection -> RoPE -> Kb
    gemm_bt<<<ggemm, 256, 0, stream>>>(Xk, Wkb, bk, proj, ROWS, HIDDEN, HIDDEN);
    rope_relayout<<<(ROWS * 512 + 255) / 256, 256, 0, stream>>>(proj, cosT, sinT, Kb);
    // V projection -> Vt (transposed)
    gemm_bt<<<ggemm, 256, 0, stream>>>(Xv, Wvb, bv, proj, ROWS, HIDDEN, HIDDEN);
    v_relayout<<<(ROWS * HIDDEN + 255) / 256, 256, 0, stream>>>(proj, Vt);

    // attention
    dim3 gattn(SEQ / 64, BH);
    attn_scores<<<gattn, 256, 0, stream>>>(Qb, Kb, P, m_arr, l_arr);
    attn_pv<<<gattn, 256, 0, stream>>>(P, Vt, m_arr, l_arr, aout);

    // output projection (bf16 attn_out @ Wo^T + bo) -> out0
    gemm_bt<<<ggemm, 256, 0, stream>>>(aout, Wob, bo, out0, ROWS, HIDDEN, HIDDEN);
}

// Round 2
// 988.696 us; speedup vs baseline: 1.2396x; 1.2396x over previous
//
#include <hip/hip_runtime.h>
#include <hip/hip_bf16.h>
#include <math.h>

// ---------- types ----------
typedef __attribute__((ext_vector_type(4))) float  f32x4;
typedef __attribute__((ext_vector_type(8))) __bf16 bf16x8;
typedef __attribute__((ext_vector_type(4))) __bf16 bf16x4;

#define HIDDEN 1024
#define HEADS 16
#define BATCH 2
#define SEQ 2048
#define ROWS (BATCH*SEQ)          // 4096
#define BH (BATCH*HEADS)          // 32
#define NQ 3072                   // fused QKV projection width
#define OUT0_ELEMS ((size_t)ROWS*HIDDEN)

// ---------- async global->LDS (16B per lane) ----------
__device__ __forceinline__ void gload_lds16(const void* g, void* l) {
    __builtin_amdgcn_global_load_lds(
        (const __attribute__((address_space(1))) void*)g,
        (__attribute__((address_space(3))) void*)l,
        16, 0, 0);
}

// ---------- cast fp32 -> bf16 (vector x4) ----------
__global__ void cast_f32_bf16(const float* __restrict__ in, __bf16* __restrict__ out, int n4) {
    int i = blockIdx.x * blockDim.x + threadIdx.x;
    if (i >= n4) return;
    float4 v = ((const float4*)in)[i];
    bf16x4 o = { (__bf16)v.x, (__bf16)v.y, (__bf16)v.z, (__bf16)v.w };
    ((bf16x4*)out)[i] = o;
}

// ---------- RoPE tables ----------
__global__ void rope_tables(float* __restrict__ cosT, float* __restrict__ sinT) {
    int i = blockIdx.x * blockDim.x + threadIdx.x;   // 2048*32
    if (i >= SEQ * 32) return;
    int s = i >> 5, f = i & 31;
    float inv = (float)pow(10000.0, -(double)f / 32.0);
    float ang = (float)s * inv;
    cosT[i] = cosf(ang);
    sinT[i] = sinf(ang);
}

// ---------- fused QKV GEMM: proj[m][0:1024]=q@Wq+bq, [1024:2048]=k@Wk+bk, [2048:3072]=v@Wv+bv
__global__ __launch_bounds__(256) void gemm_qkv(const __bf16* __restrict__ Xq,
                                                const __bf16* __restrict__ Xk,
                                                const __bf16* __restrict__ Xv,
                                                const __bf16* __restrict__ Wq,
                                                const __bf16* __restrict__ Wk,
                                                const __bf16* __restrict__ Wv,
                                                const float* __restrict__ bq,
                                                const float* __restrict__ bk,
                                                const float* __restrict__ bv,
                                                float* __restrict__ C) {
    __shared__ __bf16 As[128 * 32];
    __shared__ __bf16 Bs[128 * 32];
    const int tid = threadIdx.x, lane = tid & 63, wid = tid >> 6;
    const int wr = wid >> 1, wc = wid & 1;
    const int fr = lane & 15, fq = lane >> 4;
    const int row0 = blockIdx.x * 128, col0 = blockIdx.y * 128;
    const int sel = col0 >> 10, colr = col0 & 1023;
    const __bf16* A    = sel == 0 ? Xq : sel == 1 ? Xk : Xv;
    const __bf16* Bt   = sel == 0 ? Wq : sel == 1 ? Wk : Wv;
    const float*  bias = sel == 0 ? bq : sel == 1 ? bk : bv;

    f32x4 acc[4][4] = {};
    for (int k0 = 0; k0 < HIDDEN; k0 += 32) {
        #pragma unroll
        for (int c2 = 0; c2 < 2; ++c2) {
            int ob = wid * 2048 + c2 * 1024;
            int o  = ob + lane * 16;
            int r  = o >> 6, cb = o & 63;
            gload_lds16(A  + (size_t)(row0 + r) * HIDDEN + k0 + (cb >> 1), (char*)As + ob);
            gload_lds16(Bt + (size_t)(colr + r) * HIDDEN + k0 + (cb >> 1), (char*)Bs + ob);
        }
        __syncthreads();
        bf16x8 af[4], bfr[4];
        #pragma unroll
        for (int m = 0; m < 4; ++m) af[m]  = *(const bf16x8*)(As + (wr * 64 + m * 16 + fr) * 32 + fq * 8);
        #pragma unroll
        for (int n = 0; n < 4; ++n) bfr[n] = *(const bf16x8*)(Bs + (wc * 64 + n * 16 + fr) * 32 + fq * 8);
        #pragma unroll
        for (int m = 0; m < 4; ++m)
            #pragma unroll
            for (int n = 0; n < 4; ++n)
                acc[m][n] = __builtin_amdgcn_mfma_f32_16x16x32_bf16(af[m], bfr[n], acc[m][n], 0, 0, 0);
        __syncthreads();
    }
    #pragma unroll
    for (int m = 0; m < 4; ++m)
        #pragma unroll
        for (int n = 0; n < 4; ++n) {
            int off = wc * 64 + n * 16 + fr;
            float bvv = bias[colr + off];
            #pragma unroll
            for (int j = 0; j < 4; ++j) {
                int row = row0 + wr * 64 + m * 16 + fq * 4 + j;
                C[(size_t)row * NQ + col0 + off] = acc[m][n][j] + bvv;
            }
        }
}

// ---------- plain GEMM for output projection ----------
__global__ __launch_bounds__(256) void gemm_bt(const __bf16* __restrict__ A,
                                               const __bf16* __restrict__ Bt,
                                               const float* __restrict__ bias,
                                               float* __restrict__ C,
                                               int M, int N, int K) {
    __shared__ __bf16 As[128 * 32];
    __shared__ __bf16 Bs[128 * 32];
    const int tid = threadIdx.x, lane = tid & 63, wid = tid >> 6;
    const int wr = wid >> 1, wc = wid & 1;
    const int fr = lane & 15, fq = lane >> 4;
    const int row0 = blockIdx.x * 128, col0 = blockIdx.y * 128;

    f32x4 acc[4][4] = {};
    for (int k0 = 0; k0 < K; k0 += 32) {
        #pragma unroll
        for (int c2 = 0; c2 < 2; ++c2) {
            int ob = wid * 2048 + c2 * 1024;
            int o  = ob + lane * 16;
            int r  = o >> 6, cb = o & 63;
            gload_lds16(A  + (size_t)(row0 + r) * K + k0 + (cb >> 1), (char*)As + ob);
            gload_lds16(Bt + (size_t)(col0 + r) * K + k0 + (cb >> 1), (char*)Bs + ob);
        }
        __syncthreads();
        bf16x8 af[4], bfr[4];
        #pragma unroll
        for (int m = 0; m < 4; ++m) af[m]  = *(const bf16x8*)(As + (wr * 64 + m * 16 + fr) * 32 + fq * 8);
        #pragma unroll
        for (int n = 0; n < 4; ++n) bfr[n] = *(const bf16x8*)(Bs + (wc * 64 + n * 16 + fr) * 32 + fq * 8);
        #pragma unroll
        for (int m = 0; m < 4; ++m)
            #pragma unroll
            for (int n = 0; n < 4; ++n)
                acc[m][n] = __builtin_amdgcn_mfma_f32_16x16x32_bf16(af[m], bfr[n], acc[m][n], 0, 0, 0);
        __syncthreads();
    }
    #pragma unroll
    for (int m = 0; m < 4; ++m)
        #pragma unroll
        for (int n = 0; n < 4; ++n) {
            int col = col0 + wc * 64 + n * 16 + fr;
            float bv = bias[col];
            #pragma unroll
            for (int j = 0; j < 4; ++j) {
                int row = row0 + wr * 64 + m * 16 + fq * 4 + j;
                C[(size_t)row * N + col] = acc[m][n][j] + bv;
            }
        }
}

// ---------- RoPE + relayout Q and K together ----------
__global__ void rope_qk(const float* __restrict__ proj,
                        const float* __restrict__ cosT, const float* __restrict__ sinT,
                        __bf16* __restrict__ Qb, __bf16* __restrict__ Kb) {
    int idx = blockIdx.x * blockDim.x + threadIdx.x;   // ROWS*512 pair slots
    if (idx >= ROWS * 512) return;
    int m = idx >> 9, p = idx & 511;
    int h = p >> 5, i = p & 31;
    int b = m >> 11, s = m & 2047;
    float c = cosT[s * 32 + i], sn = sinT[s * 32 + i];
    size_t pbase = (size_t)m * NQ + h * 64 + 2 * i;
    float q1 = proj[pbase],        q2 = proj[pbase + 1];
    float k1 = proj[pbase + 1024], k2 = proj[pbase + 1025];
    size_t o = ((size_t)(b * HEADS + h) * SEQ + s) * 64 + 2 * i;
    Qb[o]     = (__bf16)(q1 * c - q2 * sn);
    Qb[o + 1] = (__bf16)(q1 * sn + q2 * c);
    Kb[o]     = (__bf16)(k1 * c - k2 * sn);
    Kb[o + 1] = (__bf16)(k1 * sn + k2 * c);
}

// ---------- V transpose via LDS: proj[:, 2048+h*64+d] -> Vt[bh][d][s] bf16 ----------
__global__ __launch_bounds__(256) void v_transpose(const float* __restrict__ proj,
                                                   __bf16* __restrict__ Vt) {
    __shared__ float T[64][65];
    const int s0 = blockIdx.x * 64, bh = blockIdx.y;
    const int b = bh >> 4, h = bh & 15;
    const int t = threadIdx.x;
    {
        int r = t >> 2, f4 = t & 3;
        const float* src = proj + (size_t)(b * SEQ + s0 + r) * NQ + 2048 + h * 64;
        #pragma unroll
        for (int i = 0; i < 4; ++i)
            *(float4*)&T[r][f4 * 4 + i * 16] = *(const float4*)(src + f4 * 4 + i * 16);
    }
    __syncthreads();
    {
        int d = t >> 2, slot = t & 3;
        __bf16* dst = Vt + ((size_t)bh * 64 + d) * SEQ + s0 + slot * 16;
        #pragma unroll
        for (int half = 0; half < 2; ++half) {
            bf16x8 o;
            #pragma unroll
            for (int i = 0; i < 8; ++i) o[i] = (__bf16)T[slot * 16 + half * 8 + i][d];
            *(bf16x8*)(dst + half * 8) = o;
        }
    }
}

// ---------- fused flash attention: stats pass + (recompute, write weights, PV) pass ----------
// grid (SEQ/64, BH), 256 thr = 4 waves x 16 q-rows each
__global__ __launch_bounds__(256) void attn_fused(const __bf16* __restrict__ Qb,
                                                  const __bf16* __restrict__ Kb,
                                                  const __bf16* __restrict__ Vt,
                                                  float* __restrict__ P,
                                                  __bf16* __restrict__ aout) {
    __shared__ __bf16 Pl[4][2][16 * 40];   // per-wave, double-buffered, padded stride 40
    const int qt = blockIdx.x, bh = blockIdx.y;
    const int lane = threadIdx.x & 63, w = threadIdx.x >> 6;
    const int fr = lane & 15, fq = lane >> 4;
    const int rowBase = qt * 64 + w * 16;

    const size_t qoff = ((size_t)bh * SEQ + rowBase + fr) * 64;
    const bf16x8 aq0 = *(const bf16x8*)(Qb + qoff + fq * 8);
    const bf16x8 aq1 = *(const bf16x8*)(Qb + qoff + 32 + fq * 8);

    const __bf16* Kbh = Kb + (size_t)bh * SEQ * 64;
    const __bf16* Vbh = Vt + (size_t)bh * 64 * SEQ;
    float* Pbh = P + (size_t)bh * SEQ * SEQ;

    const int nkt = rowBase / 32 + 1;      // 32-col chunks covering the causal span

    // ---- pass 1: online (m,l) ----
    float mr[4] = { -INFINITY, -INFINITY, -INFINITY, -INFINITY };
    float lr[4] = { 0.f, 0.f, 0.f, 0.f };
    for (int kt = 0; kt < nkt; ++kt) {
        #pragma unroll
        for (int t2 = 0; t2 < 2; ++t2) {
            const __bf16* kp = Kbh + (size_t)(kt * 32 + t2 * 16 + fr) * 64;
            bf16x8 bk0 = *(const bf16x8*)(kp + fq * 8);
            bf16x8 bk1 = *(const bf16x8*)(kp + 32 + fq * 8);
            f32x4 sc = { 0.f, 0.f, 0.f, 0.f };
            sc = __builtin_amdgcn_mfma_f32_16x16x32_bf16(aq0, bk0, sc, 0, 0, 0);
            sc = __builtin_amdgcn_mfma_f32_16x16x32_bf16(aq1, bk1, sc, 0, 0, 0);
            const int col = kt * 32 + t2 * 16 + fr;
            #pragma unroll
            for (int j = 0; j < 4; ++j) {
                int row = rowBase + fq * 4 + j;
                float s = sc[j] * 0.125f;
                if (col > row) s = -1e9f;
                float nm = fmaxf(mr[j], s);
                lr[j] = lr[j] * __expf(mr[j] - nm) + __expf(s - nm);
                mr[j] = nm;
            }
        }
    }
    // reduce over the 16 fr-lanes (lane bits 0..3)
    #pragma unroll
    for (int j = 0; j < 4; ++j) {
        float m = mr[j], l = lr[j];
        #pragma unroll
        for (int d = 1; d < 16; d <<= 1) {
            float mo = __shfl_xor(m, d, 64);
            float lo = __shfl_xor(l, d, 64);
            float nm = fmaxf(m, mo);
            l = l * __expf(m - nm) + lo * __expf(mo - nm);
            m = nm;
        }
        mr[j] = m;
        lr[j] = 1.0f / l;
    }

    // ---- pass 2: recompute, write normalized weights, PV ----
    f32x4 acc[4] = {};
    for (int kt = 0; kt < nkt; ++kt) {
        __bf16* pl = &Pl[w][kt & 1][0];
        #pragma unroll
        for (int t2 = 0; t2 < 2; ++t2) {
            const __bf16* kp = Kbh + (size_t)(kt * 32 + t2 * 16 + fr) * 64;
            bf16x8 bk0 = *(const bf16x8*)(kp + fq * 8);
            bf16x8 bk1 = *(const bf16x8*)(kp + 32 + fq * 8);
            f32x4 sc = { 0.f, 0.f, 0.f, 0.f };
            sc = __builtin_amdgcn_mfma_f32_16x16x32_bf16(aq0, bk0, sc, 0, 0, 0);
            sc = __builtin_amdgcn_mfma_f32_16x16x32_bf16(aq1, bk1, sc, 0, 0, 0);
            const int col = kt * 32 + t2 * 16 + fr;
            #pragma unroll
            for (int j = 0; j < 4; ++j) {
                int row = rowBase + fq * 4 + j;
                float s = sc[j] * 0.125f;
                if (col > row) s = -1e9f;
                float p = __expf(s - mr[j]) * lr[j];
                Pbh[(size_t)row * SEQ + col] = p;
                pl[(fq * 4 + j) * 40 + t2 * 16 + fr] = (__bf16)p;
            }
        }
        // A-fragment read (row=fr, k=fq*8..+7) + PV MFMA
        bf16x8 pa = *(const bf16x8*)(pl + fr * 40 + fq * 8);
        #pragma unroll
        for (int nd = 0; nd < 4; ++nd) {
            bf16x8 bv = *(const bf16x8*)(Vbh + (size_t)(nd * 16 + fr) * SEQ + kt * 32 + fq * 8);
            acc[nd] = __builtin_amdgcn_mfma_f32_16x16x32_bf16(pa, bv, acc[nd], 0, 0, 0);
        }
    }

    // ---- zero-fill uncovered upper-triangle columns ----
    {
        int r = rowBase + (lane >> 2);
        float4 z = { 0.f, 0.f, 0.f, 0.f };
        for (int c = nkt * 32 + (lane & 3) * 4; c < SEQ; c += 16)
            *(float4*)(Pbh + (size_t)r * SEQ + c) = z;
    }

    // ---- write attn_out bf16 [ROWS][HIDDEN] ----
    const int b = bh >> 4, h = bh & 15;
    #pragma unroll
    for (int nd = 0; nd < 4; ++nd)
        #pragma unroll
        for (int j = 0; j < 4; ++j) {
            int qrow = rowBase + fq * 4 + j;
            aout[((size_t)(b * SEQ + qrow)) * HIDDEN + h * 64 + nd * 16 + fr] = (__bf16)acc[nd][j];
        }
}

// ---------- host launch ----------
extern "C" void kernel_launch(void* const* d_in, const int* in_sizes, int n_in,
                              void* d_out, int out_size, void* d_ws, size_t ws_size,
                              hipStream_t stream) {
    const float* query = (const float*)d_in[0];
    const float* key   = (const float*)d_in[1];
    const float* value = (const float*)d_in[2];
    const float* Wq = (const float*)d_in[3];
    const float* bq = (const float*)d_in[4];
    const float* Wk = (const float*)d_in[5];
    const float* bk = (const float*)d_in[6];
    const float* Wv = (const float*)d_in[7];
    const float* bv = (const float*)d_in[8];
    const float* Wo = (const float*)d_in[9];
    const float* bo = (const float*)d_in[10];

    float* out0 = (float*)d_out;                       // [4096][1024]
    float* P    = (float*)d_out + OUT0_ELEMS;          // [32][2048][2048]

    char* p = (char*)d_ws;
    auto alloc = [&](size_t bytes) { char* r = p; p += (bytes + 255) & ~(size_t)255; return r; };
    float*  cosT = (float*)alloc(SEQ * 32 * 4);
    float*  sinT = (float*)alloc(SEQ * 32 * 4);
    __bf16* Xq   = (__bf16*)alloc(OUT0_ELEMS * 2);
    __bf16* Xk   = (__bf16*)alloc(OUT0_ELEMS * 2);
    __bf16* Xv   = (__bf16*)alloc(OUT0_ELEMS * 2);
    __bf16* Wqb  = (__bf16*)alloc((size_t)HIDDEN * HIDDEN * 2);
    __bf16* Wkb  = (__bf16*)alloc((size_t)HIDDEN * HIDDEN * 2);
    __bf16* Wvb  = (__bf16*)alloc((size_t)HIDDEN * HIDDEN * 2);
    __bf16* Wob  = (__bf16*)alloc((size_t)HIDDEN * HIDDEN * 2);
    float*  proj = (float*)alloc((size_t)ROWS * NQ * 4);          // [4096][3072]
    __bf16* Qb   = (__bf16*)alloc((size_t)BH * SEQ * 64 * 2);
    __bf16* Kb   = (__bf16*)alloc((size_t)BH * SEQ * 64 * 2);
    __bf16* Vt   = (__bf16*)alloc((size_t)BH * SEQ * 64 * 2);
    __bf16* aout = (__bf16*)alloc(OUT0_ELEMS * 2);

    rope_tables<<<(SEQ * 32 + 255) / 256, 256, 0, stream>>>(cosT, sinT);

    cast_f32_bf16<<<(ROWS * HIDDEN / 4 + 255) / 256, 256, 0, stream>>>(query, Xq, ROWS * HIDDEN / 4);
    cast_f32_bf16<<<(ROWS * HIDDEN / 4 + 255) / 256, 256, 0, stream>>>(key,   Xk, ROWS * HIDDEN / 4);
    cast_f32_bf16<<<(ROWS * HIDDEN / 4 + 255) / 256, 256, 0, stream>>>(value, Xv, ROWS * HIDDEN / 4);
    cast_f32_bf16<<<(HIDDEN * HIDDEN / 4 + 255) / 256, 256, 0, stream>>>(Wq, Wqb, HIDDEN * HIDDEN / 4);
    cast_f32_bf16<<<(HIDDEN * HIDDEN / 4 + 255) / 256, 256, 0, stream>>>(Wk, Wkb, HIDDEN * HIDDEN / 4);
    cast_f32_bf16<<<(HIDDEN * HIDDEN / 4 + 255) / 256, 256, 0, stream>>>(Wv, Wvb, HIDDEN * HIDDEN / 4);
    cast_f32_bf16<<<(HIDDEN * HIDDEN / 4 + 255) / 256, 256, 0, stream>>>(Wo, Wob, HIDDEN * HIDDEN / 4);

    // fused QKV projection
    dim3 gqkv(ROWS / 128, NQ / 128);
    gemm_qkv<<<gqkv, 256, 0, stream>>>(Xq, Xk, Xv, Wqb, Wkb, Wvb, bq, bk, bv, proj);

    // RoPE relayout (Q,K) + V transpose
    rope_qk<<<(ROWS * 512 + 255) / 256, 256, 0, stream>>>(proj, cosT, sinT, Qb, Kb);
    dim3 gvt(SEQ / 64, BH);
    v_transpose<<<gvt, 256, 0, stream>>>(proj, Vt);

    // fused attention (writes weights incl. zero upper triangle, and attn_out)
    dim3 gattn(SEQ / 64, BH);
    attn_fused<<<gattn, 256, 0, stream>>>(Qb, Kb, Vt, P, aout);

    // output projection
    dim3 ggemm(ROWS / 128, HIDDEN / 128);
    gemm_bt<<<ggemm, 256, 0, stream>>>(aout, Wob, bo, out0, ROWS, HIDDEN, HIDDEN);
}